// Round 8
// baseline (433.989 us; speedup 1.0000x reference)
//
#include <hip/hip_runtime.h>
#include <math.h>

#define N_NODES 50000
#define N_EDGES 800000
#define IN_F 128
#define OUT_F 64
#define LRELU_ALPHA 0.2f

#define NPB 128                              // nodes per bucket (power of 2)
#define NBUCK ((N_NODES + NPB - 1) / NPB)    // 391
#define EPT 8                                // edges per thread (hist/scatter)
#define NBT ((N_EDGES / EPT + 255) / 256)    // 391 blocks

__device__ inline float wred_max(float v) {
#pragma unroll
    for (int o = 32; o > 0; o >>= 1) v = fmaxf(v, __shfl_down(v, o, 64));
    return v;
}
__device__ inline float wred_sum(float v) {
#pragma unroll
    for (int o = 32; o > 0; o >>= 1) v += __shfl_down(v, o, 64);
    return v;
}

// K1: Wh = x @ W, register-tiled: 64x64 tile per block, 4x4 per thread.
// Block 0 additionally zeroes the bucket-histogram counters.
__global__ __launch_bounds__(256, 2) void k_wh(const float* __restrict__ x,
                                               const float* __restrict__ W,
                                               const float* __restrict__ a,
                                               float* __restrict__ Wh,
                                               float* __restrict__ sv,
                                               float* __restrict__ tv,
                                               int* __restrict__ bcnt) {
    __shared__ float xs[64 * 128];  // x tile, XOR-swizzled
    __shared__ float Ws[128 * 64];  // W, natural layout

    const int tid = threadIdx.x;
    const int row0 = blockIdx.x * 64;

    if (blockIdx.x == 0)
        for (int i = tid; i < NBUCK; i += 256) bcnt[i] = 0;

    for (int i = tid; i < 64 * 32; i += 256) {
        int rl = i >> 5, c4 = (i & 31) << 2;
        int r = row0 + rl;
        float4 v = make_float4(0.f, 0.f, 0.f, 0.f);
        if (r < N_NODES) v = *reinterpret_cast<const float4*>(x + (size_t)r * IN_F + c4);
        int sw = c4 ^ ((rl & 7) << 2);
        *reinterpret_cast<float4*>(&xs[rl * 128 + sw]) = v;
    }
    for (int i = tid; i < 128 * 16; i += 256) {
        int k = i >> 4, c4 = (i & 15) << 2;
        *reinterpret_cast<float4*>(&Ws[k * 64 + c4]) =
            *reinterpret_cast<const float4*>(W + k * 64 + c4);
    }
    __syncthreads();

    const int tx = tid & 15;
    const int ty = tid >> 4;
    const int c0 = tx << 2;
    const int rl0 = ty << 2;

    float acc[4][4] = {};
#pragma unroll 4
    for (int k = 0; k < 128; ++k) {
        float4 b = *reinterpret_cast<const float4*>(&Ws[k * 64 + c0]);
        float a0 = xs[(rl0 + 0) * 128 + (k ^ (((rl0 + 0) & 7) << 2))];
        float a1 = xs[(rl0 + 1) * 128 + (k ^ (((rl0 + 1) & 7) << 2))];
        float a2 = xs[(rl0 + 2) * 128 + (k ^ (((rl0 + 2) & 7) << 2))];
        float a3 = xs[(rl0 + 3) * 128 + (k ^ (((rl0 + 3) & 7) << 2))];
        acc[0][0] = fmaf(a0, b.x, acc[0][0]);
        acc[0][1] = fmaf(a0, b.y, acc[0][1]);
        acc[0][2] = fmaf(a0, b.z, acc[0][2]);
        acc[0][3] = fmaf(a0, b.w, acc[0][3]);
        acc[1][0] = fmaf(a1, b.x, acc[1][0]);
        acc[1][1] = fmaf(a1, b.y, acc[1][1]);
        acc[1][2] = fmaf(a1, b.z, acc[1][2]);
        acc[1][3] = fmaf(a1, b.w, acc[1][3]);
        acc[2][0] = fmaf(a2, b.x, acc[2][0]);
        acc[2][1] = fmaf(a2, b.y, acc[2][1]);
        acc[2][2] = fmaf(a2, b.z, acc[2][2]);
        acc[2][3] = fmaf(a2, b.w, acc[2][3]);
        acc[3][0] = fmaf(a3, b.x, acc[3][0]);
        acc[3][1] = fmaf(a3, b.y, acc[3][1]);
        acc[3][2] = fmaf(a3, b.z, acc[3][2]);
        acc[3][3] = fmaf(a3, b.w, acc[3][3]);
    }

    float at[4], ab[4];
#pragma unroll
    for (int i = 0; i < 4; i++) {
        at[i] = a[c0 + i];
        ab[i] = a[OUT_F + c0 + i];
    }

#pragma unroll
    for (int ri = 0; ri < 4; ++ri) {
        int r = row0 + rl0 + ri;
        float ps = 0.0f, pt = 0.0f;
#pragma unroll
        for (int ci = 0; ci < 4; ++ci) {
            ps = fmaf(acc[ri][ci], at[ci], ps);
            pt = fmaf(acc[ri][ci], ab[ci], pt);
        }
#pragma unroll
        for (int o = 1; o < 16; o <<= 1) {
            ps += __shfl_xor(ps, o, 64);
            pt += __shfl_xor(pt, o, 64);
        }
        if (r < N_NODES) {
            *reinterpret_cast<float4*>(Wh + (size_t)r * OUT_F + c0) =
                make_float4(acc[ri][0], acc[ri][1], acc[ri][2], acc[ri][3]);
            if (tx == 0) { sv[r] = ps; tv[r] = pt; }
        }
    }
}

// bucket histogram: LDS pre-aggregation, then one global atomic per bucket
__global__ __launch_bounds__(256) void k_bhist(const int* __restrict__ src,
                                               int* __restrict__ bcnt) {
    __shared__ int c[NBUCK];
    for (int i = threadIdx.x; i < NBUCK; i += 256) c[i] = 0;
    __syncthreads();
    int t = blockIdx.x * 256 + threadIdx.x;
    int j0 = t * EPT;
    if (j0 < N_EDGES) {
        int4 a4 = *reinterpret_cast<const int4*>(src + j0);
        int4 b4 = *reinterpret_cast<const int4*>(src + j0 + 4);
        atomicAdd(&c[a4.x >> 7], 1);
        atomicAdd(&c[a4.y >> 7], 1);
        atomicAdd(&c[a4.z >> 7], 1);
        atomicAdd(&c[a4.w >> 7], 1);
        atomicAdd(&c[b4.x >> 7], 1);
        atomicAdd(&c[b4.y >> 7], 1);
        atomicAdd(&c[b4.z >> 7], 1);
        atomicAdd(&c[b4.w >> 7], 1);
    }
    __syncthreads();
    for (int i = threadIdx.x; i < NBUCK; i += 256) {
        int v = c[i];
        if (v) atomicAdd(&bcnt[i], v);
    }
}

// exclusive scan of 391 bucket counts (single 512-thread block)
__global__ __launch_bounds__(512) void k_bscan(const int* __restrict__ bcnt,
                                               int* __restrict__ bbase,
                                               int* __restrict__ cursor) {
    __shared__ int s[512];
    int t = threadIdx.x;
    int c = (t < NBUCK) ? bcnt[t] : 0;
    s[t] = c;
    __syncthreads();
#pragma unroll
    for (int o = 1; o < 512; o <<= 1) {
        int v = (t >= o) ? s[t - o] : 0;
        __syncthreads();
        s[t] += v;
        __syncthreads();
    }
    if (t < NBUCK) {
        int ex = s[t] - c;
        bbase[t] = ex;
        cursor[t] = ex;
    }
    if (t == 0) bbase[NBUCK] = N_EDGES;
}

// bucket scatter: LDS ranks + one global reserve atomic per (block,bucket),
// contiguous run writes; fused edge score + online-softmax block stats.
__global__ __launch_bounds__(256) void k_binscatter(const int* __restrict__ src,
                                                    const int* __restrict__ dst,
                                                    const float* __restrict__ sv,
                                                    const float* __restrict__ tv,
                                                    int* __restrict__ cursor,
                                                    int2* __restrict__ rec,
                                                    float* __restrict__ pmax,
                                                    float* __restrict__ psum) {
    __shared__ int lcnt[NBUCK];
    __shared__ int lbase[NBUCK];
    const int tid = threadIdx.x;
    for (int i = tid; i < NBUCK; i += 256) lcnt[i] = 0;
    __syncthreads();

    int t = blockIdx.x * 256 + tid;
    int j0 = t * EPT;
    bool ok = (j0 < N_EDGES);  // N_EDGES % EPT == 0 -> all-or-nothing per thread

    int s_[EPT], d_[EPT], rk[EPT];
    float v[EPT];
    float lmax = -INFINITY;
    if (ok) {
        int4 a4 = *reinterpret_cast<const int4*>(src + j0);
        int4 b4 = *reinterpret_cast<const int4*>(src + j0 + 4);
        int4 c4 = *reinterpret_cast<const int4*>(dst + j0);
        int4 e4 = *reinterpret_cast<const int4*>(dst + j0 + 4);
        s_[0] = a4.x; s_[1] = a4.y; s_[2] = a4.z; s_[3] = a4.w;
        s_[4] = b4.x; s_[5] = b4.y; s_[6] = b4.z; s_[7] = b4.w;
        d_[0] = c4.x; d_[1] = c4.y; d_[2] = c4.z; d_[3] = c4.w;
        d_[4] = e4.x; d_[5] = e4.y; d_[6] = e4.z; d_[7] = e4.w;
        float svv[EPT], tvv[EPT];
#pragma unroll
        for (int k = 0; k < EPT; k++) svv[k] = sv[s_[k]];
#pragma unroll
        for (int k = 0; k < EPT; k++) tvv[k] = tv[d_[k]];
#pragma unroll
        for (int k = 0; k < EPT; k++) {
            float vv = svv[k] + tvv[k];
            vv = vv > 0.0f ? vv : LRELU_ALPHA * vv;
            v[k] = vv;
            lmax = fmaxf(lmax, vv);
        }
#pragma unroll
        for (int k = 0; k < EPT; k++) rk[k] = atomicAdd(&lcnt[s_[k] >> 7], 1);
    }
    __syncthreads();

    for (int i = tid; i < NBUCK; i += 256) {
        int c = lcnt[i];
        lbase[i] = c ? atomicAdd(&cursor[i], c) : 0;
    }
    __syncthreads();

    if (ok) {
#pragma unroll
        for (int k = 0; k < EPT; k++) {
            int b = s_[k] >> 7;
            rec[lbase[b] + rk[k]] =
                make_int2(d_[k] | ((s_[k] & (NPB - 1)) << 16), __float_as_int(v[k]));
        }
    }

    // online-softmax block stats
    float wm = wred_max(lmax);
    wm = __shfl(wm, 0, 64);
    float ev = 0.0f;
    if (ok) {
#pragma unroll
        for (int k = 0; k < EPT; k++) ev += expf(v[k] - wm);
    }
    float wsum = wred_sum(ev);

    __shared__ float rmx[4], rsm[4];
    if ((tid & 63) == 0) {
        rmx[tid >> 6] = wm;
        rsm[tid >> 6] = wsum;
    }
    __syncthreads();
    if (tid == 0) {
        float bm = fmaxf(fmaxf(rmx[0], rmx[1]), fmaxf(rmx[2], rmx[3]));
        float bs = 0.0f;
#pragma unroll
        for (int i = 0; i < 4; i++)
            bs += (rmx[i] == -INFINITY) ? 0.0f : rsm[i] * expf(rmx[i] - bm);
        pmax[blockIdx.x] = bm;
        psum[blockIdx.x] = bs;
    }
}

// combine block stats: g[0]=gmax, g[1]=1/sum
__global__ __launch_bounds__(1024) void k_rcombine(const float* __restrict__ pmax,
                                                   const float* __restrict__ psum,
                                                   int n, float* __restrict__ g) {
    __shared__ float red[16];
    __shared__ float gm_s;
    int t = threadIdx.x;
    float lmax = -INFINITY;
    for (int i = t; i < n; i += 1024) lmax = fmaxf(lmax, pmax[i]);
    float wm = wred_max(lmax);
    if ((t & 63) == 0) red[t >> 6] = wm;
    __syncthreads();
    if (t == 0) {
        float m = red[0];
        for (int i = 1; i < 16; i++) m = fmaxf(m, red[i]);
        gm_s = m;
    }
    __syncthreads();
    float gm = gm_s;
    float lsum = 0.0f;
    for (int i = t; i < n; i += 1024)
        lsum += (pmax[i] == -INFINITY) ? 0.0f : psum[i] * expf(pmax[i] - gm);
    float ws = wred_sum(lsum);
    __syncthreads();
    if ((t & 63) == 0) red[t >> 6] = ws;
    __syncthreads();
    if (t == 0) {
        float s = 0.0f;
        for (int i = 0; i < 16; i++) s += red[i];
        g[0] = gm;
        g[1] = 1.0f / s;
    }
}

// bucket gather: one block per bucket; LDS float accumulators (128 nodes x 64 f),
// ds_add_f32 per lane; exp/ginv/ELU fused; coalesced out write.
__global__ __launch_bounds__(512) void k_bgather(const int* __restrict__ bbase,
                                                 const int2* __restrict__ rec,
                                                 const float* __restrict__ g,
                                                 const float* __restrict__ Wh,
                                                 float* __restrict__ out) {
    __shared__ float acc[NPB * OUT_F];  // 32 KB
    __shared__ int2 stage[512];         // 4 KB

    const int tid = threadIdx.x;
    const int lane = tid & 63, w = tid >> 6;
    const int b = blockIdx.x;
    const float gm = g[0], ginv = g[1];

    for (int i = tid; i < NPB * OUT_F; i += 512) acc[i] = 0.0f;
    const int e0 = bbase[b], e1 = bbase[b + 1];
    __syncthreads();

    for (int base = e0; base < e1; base += 512) {
        int m = e1 - base;
        if (m > 512) m = 512;
        if (tid < m) stage[tid] = rec[base + tid];
        __syncthreads();

        int mw = m - w * 64;
        if (mw < 0) mw = 0;
        if (mw > 64) mw = 64;
        const int sb = w * 64;
        int i = 0;
        for (; i + 3 < mw; i += 4) {
            int2 r0 = stage[sb + i], r1 = stage[sb + i + 1];
            int2 r2 = stage[sb + i + 2], r3 = stage[sb + i + 3];
            int dd0 = r0.x & 0xFFFF, l0 = (r0.x >> 16) & (NPB - 1);
            int dd1 = r1.x & 0xFFFF, l1 = (r1.x >> 16) & (NPB - 1);
            int dd2 = r2.x & 0xFFFF, l2 = (r2.x >> 16) & (NPB - 1);
            int dd3 = r3.x & 0xFFFF, l3 = (r3.x >> 16) & (NPB - 1);
            float w0 = Wh[(size_t)dd0 * OUT_F + lane];
            float w1 = Wh[(size_t)dd1 * OUT_F + lane];
            float w2 = Wh[(size_t)dd2 * OUT_F + lane];
            float w3 = Wh[(size_t)dd3 * OUT_F + lane];
            float a0 = expf(__int_as_float(r0.y) - gm);
            float a1 = expf(__int_as_float(r1.y) - gm);
            float a2 = expf(__int_as_float(r2.y) - gm);
            float a3 = expf(__int_as_float(r3.y) - gm);
            atomicAdd(&acc[(l0 << 6) + lane], a0 * w0);
            atomicAdd(&acc[(l1 << 6) + lane], a1 * w1);
            atomicAdd(&acc[(l2 << 6) + lane], a2 * w2);
            atomicAdd(&acc[(l3 << 6) + lane], a3 * w3);
        }
        for (; i < mw; i++) {
            int2 r0 = stage[sb + i];
            int dd0 = r0.x & 0xFFFF, l0 = (r0.x >> 16) & (NPB - 1);
            float w0 = Wh[(size_t)dd0 * OUT_F + lane];
            float a0 = expf(__int_as_float(r0.y) - gm);
            atomicAdd(&acc[(l0 << 6) + lane], a0 * w0);
        }
        __syncthreads();
    }

    // write out: float4-coalesced, ELU fused
    const int n0 = b * NPB;
    int nn = N_NODES - n0;
    if (nn > NPB) nn = NPB;
    for (int i = tid; i < nn * 16; i += 512) {
        int ln = i >> 4, f4 = (i & 15) << 2;
        float4 v4 = *reinterpret_cast<float4*>(&acc[(ln << 6) + f4]);
        v4.x *= ginv; v4.y *= ginv; v4.z *= ginv; v4.w *= ginv;
        v4.x = v4.x > 0.0f ? v4.x : expm1f(v4.x);
        v4.y = v4.y > 0.0f ? v4.y : expm1f(v4.y);
        v4.z = v4.z > 0.0f ? v4.z : expm1f(v4.z);
        v4.w = v4.w > 0.0f ? v4.w : expm1f(v4.w);
        *reinterpret_cast<float4*>(out + (size_t)(n0 + ln) * OUT_F + f4) = v4;
    }
}

extern "C" void kernel_launch(void* const* d_in, const int* in_sizes, int n_in,
                              void* d_out, int out_size, void* d_ws, size_t ws_size,
                              hipStream_t stream) {
    const float* x  = (const float*)d_in[0];
    const int*   ei = (const int*)d_in[1];
    const float* W  = (const float*)d_in[2];
    const float* a  = (const float*)d_in[3];
    float* out = (float*)d_out;

    const int* src = ei;            // edge_index[0]
    const int* dst = ei + N_EDGES;  // edge_index[1]

    float* ws     = (float*)d_ws;
    float* Wh     = ws;                               // 3,200,000 f
    float* sv     = Wh + (size_t)N_NODES * OUT_F;     // 50,000 f
    float* tv     = sv + N_NODES;                     // 50,000 f
    float* pmax   = tv + N_NODES;                     // 512 f
    float* psum   = pmax + 512;                       // 512 f
    float* g      = psum + 512;                       // 2 f (gmax, ginv)
    int*   bcnt   = (int*)(g + 2);                    // NBUCK i
    int*   bbase  = bcnt + NBUCK;                     // NBUCK+1 i
    int*   cursor = bbase + NBUCK + 1;                // NBUCK i
    // 16B-align rec
    size_t used = (size_t)((char*)(cursor + NBUCK) - (char*)d_ws);
    used = (used + 15) & ~(size_t)15;
    int2*  rec  = (int2*)((char*)d_ws + used);        // 800,000 int2 = 6.4 MB

    k_wh<<<(N_NODES + 63) / 64, 256, 0, stream>>>(x, W, a, Wh, sv, tv, bcnt);
    k_bhist<<<NBT, 256, 0, stream>>>(src, bcnt);
    k_bscan<<<1, 512, 0, stream>>>(bcnt, bbase, cursor);
    k_binscatter<<<NBT, 256, 0, stream>>>(src, dst, sv, tv, cursor, rec, pmax, psum);
    k_rcombine<<<1, 1024, 0, stream>>>(pmax, psum, NBT, g);
    k_bgather<<<NBUCK, 512, 0, stream>>>(bbase, rec, g, Wh, out);
}

// Round 9
// 181.320 us; speedup vs baseline: 2.3935x; 2.3935x over previous
//
#include <hip/hip_runtime.h>
#include <math.h>

#define N_NODES 50000
#define N_EDGES 800000
#define IN_F 128
#define OUT_F 64
#define LRELU_ALPHA 0.2f

#define NPB 128                              // nodes per bucket (power of 2)
#define NBUCK ((N_NODES + NPB - 1) / NPB)    // 391
#define EPT 8                                // edges per thread (hist/scatter)
#define NBT ((N_EDGES / EPT + 255) / 256)    // 391 blocks

__device__ inline float wred_max(float v) {
#pragma unroll
    for (int o = 32; o > 0; o >>= 1) v = fmaxf(v, __shfl_down(v, o, 64));
    return v;
}
__device__ inline float wred_sum(float v) {
#pragma unroll
    for (int o = 32; o > 0; o >>= 1) v += __shfl_down(v, o, 64);
    return v;
}

// K1: Wh = x @ W, register-tiled: 64x64 tile per block, 4x4 per thread.
// Block 0 additionally zeroes the bucket-histogram counters.
__global__ __launch_bounds__(256, 2) void k_wh(const float* __restrict__ x,
                                               const float* __restrict__ W,
                                               const float* __restrict__ a,
                                               float* __restrict__ Wh,
                                               float* __restrict__ sv,
                                               float* __restrict__ tv,
                                               int* __restrict__ bcnt) {
    __shared__ float xs[64 * 128];  // x tile, XOR-swizzled
    __shared__ float Ws[128 * 64];  // W, natural layout

    const int tid = threadIdx.x;
    const int row0 = blockIdx.x * 64;

    if (blockIdx.x == 0)
        for (int i = tid; i < NBUCK; i += 256) bcnt[i] = 0;

    for (int i = tid; i < 64 * 32; i += 256) {
        int rl = i >> 5, c4 = (i & 31) << 2;
        int r = row0 + rl;
        float4 v = make_float4(0.f, 0.f, 0.f, 0.f);
        if (r < N_NODES) v = *reinterpret_cast<const float4*>(x + (size_t)r * IN_F + c4);
        int sw = c4 ^ ((rl & 7) << 2);
        *reinterpret_cast<float4*>(&xs[rl * 128 + sw]) = v;
    }
    for (int i = tid; i < 128 * 16; i += 256) {
        int k = i >> 4, c4 = (i & 15) << 2;
        *reinterpret_cast<float4*>(&Ws[k * 64 + c4]) =
            *reinterpret_cast<const float4*>(W + k * 64 + c4);
    }
    __syncthreads();

    const int tx = tid & 15;
    const int ty = tid >> 4;
    const int c0 = tx << 2;
    const int rl0 = ty << 2;

    float acc[4][4] = {};
#pragma unroll 4
    for (int k = 0; k < 128; ++k) {
        float4 b = *reinterpret_cast<const float4*>(&Ws[k * 64 + c0]);
        float a0 = xs[(rl0 + 0) * 128 + (k ^ (((rl0 + 0) & 7) << 2))];
        float a1 = xs[(rl0 + 1) * 128 + (k ^ (((rl0 + 1) & 7) << 2))];
        float a2 = xs[(rl0 + 2) * 128 + (k ^ (((rl0 + 2) & 7) << 2))];
        float a3 = xs[(rl0 + 3) * 128 + (k ^ (((rl0 + 3) & 7) << 2))];
        acc[0][0] = fmaf(a0, b.x, acc[0][0]);
        acc[0][1] = fmaf(a0, b.y, acc[0][1]);
        acc[0][2] = fmaf(a0, b.z, acc[0][2]);
        acc[0][3] = fmaf(a0, b.w, acc[0][3]);
        acc[1][0] = fmaf(a1, b.x, acc[1][0]);
        acc[1][1] = fmaf(a1, b.y, acc[1][1]);
        acc[1][2] = fmaf(a1, b.z, acc[1][2]);
        acc[1][3] = fmaf(a1, b.w, acc[1][3]);
        acc[2][0] = fmaf(a2, b.x, acc[2][0]);
        acc[2][1] = fmaf(a2, b.y, acc[2][1]);
        acc[2][2] = fmaf(a2, b.z, acc[2][2]);
        acc[2][3] = fmaf(a2, b.w, acc[2][3]);
        acc[3][0] = fmaf(a3, b.x, acc[3][0]);
        acc[3][1] = fmaf(a3, b.y, acc[3][1]);
        acc[3][2] = fmaf(a3, b.z, acc[3][2]);
        acc[3][3] = fmaf(a3, b.w, acc[3][3]);
    }

    float at[4], ab[4];
#pragma unroll
    for (int i = 0; i < 4; i++) {
        at[i] = a[c0 + i];
        ab[i] = a[OUT_F + c0 + i];
    }

#pragma unroll
    for (int ri = 0; ri < 4; ++ri) {
        int r = row0 + rl0 + ri;
        float ps = 0.0f, pt = 0.0f;
#pragma unroll
        for (int ci = 0; ci < 4; ++ci) {
            ps = fmaf(acc[ri][ci], at[ci], ps);
            pt = fmaf(acc[ri][ci], ab[ci], pt);
        }
#pragma unroll
        for (int o = 1; o < 16; o <<= 1) {
            ps += __shfl_xor(ps, o, 64);
            pt += __shfl_xor(pt, o, 64);
        }
        if (r < N_NODES) {
            *reinterpret_cast<float4*>(Wh + (size_t)r * OUT_F + c0) =
                make_float4(acc[ri][0], acc[ri][1], acc[ri][2], acc[ri][3]);
            if (tx == 0) { sv[r] = ps; tv[r] = pt; }
        }
    }
}

// bucket histogram: LDS pre-aggregation, then one global atomic per bucket
__global__ __launch_bounds__(256) void k_bhist(const int* __restrict__ src,
                                               int* __restrict__ bcnt) {
    __shared__ int c[NBUCK];
    for (int i = threadIdx.x; i < NBUCK; i += 256) c[i] = 0;
    __syncthreads();
    int t = blockIdx.x * 256 + threadIdx.x;
    int j0 = t * EPT;
    if (j0 < N_EDGES) {
        int4 a4 = *reinterpret_cast<const int4*>(src + j0);
        int4 b4 = *reinterpret_cast<const int4*>(src + j0 + 4);
        atomicAdd(&c[a4.x >> 7], 1);
        atomicAdd(&c[a4.y >> 7], 1);
        atomicAdd(&c[a4.z >> 7], 1);
        atomicAdd(&c[a4.w >> 7], 1);
        atomicAdd(&c[b4.x >> 7], 1);
        atomicAdd(&c[b4.y >> 7], 1);
        atomicAdd(&c[b4.z >> 7], 1);
        atomicAdd(&c[b4.w >> 7], 1);
    }
    __syncthreads();
    for (int i = threadIdx.x; i < NBUCK; i += 256) {
        int v = c[i];
        if (v) atomicAdd(&bcnt[i], v);
    }
}

// exclusive scan of 391 bucket counts (single 512-thread block)
__global__ __launch_bounds__(512) void k_bscan(const int* __restrict__ bcnt,
                                               int* __restrict__ bbase,
                                               int* __restrict__ cursor) {
    __shared__ int s[512];
    int t = threadIdx.x;
    int c = (t < NBUCK) ? bcnt[t] : 0;
    s[t] = c;
    __syncthreads();
#pragma unroll
    for (int o = 1; o < 512; o <<= 1) {
        int v = (t >= o) ? s[t - o] : 0;
        __syncthreads();
        s[t] += v;
        __syncthreads();
    }
    if (t < NBUCK) {
        int ex = s[t] - c;
        bbase[t] = ex;
        cursor[t] = ex;
    }
    if (t == 0) bbase[NBUCK] = N_EDGES;
}

// bucket scatter: LDS ranks + one global reserve atomic per (block,bucket),
// contiguous run writes; fused edge score + online-softmax block stats.
__global__ __launch_bounds__(256) void k_binscatter(const int* __restrict__ src,
                                                    const int* __restrict__ dst,
                                                    const float* __restrict__ sv,
                                                    const float* __restrict__ tv,
                                                    int* __restrict__ cursor,
                                                    int2* __restrict__ rec,
                                                    float* __restrict__ pmax,
                                                    float* __restrict__ psum) {
    __shared__ int lcnt[NBUCK];
    __shared__ int lbase[NBUCK];
    const int tid = threadIdx.x;
    for (int i = tid; i < NBUCK; i += 256) lcnt[i] = 0;
    __syncthreads();

    int t = blockIdx.x * 256 + tid;
    int j0 = t * EPT;
    bool ok = (j0 < N_EDGES);  // N_EDGES % EPT == 0 -> all-or-nothing per thread

    int s_[EPT], d_[EPT], rk[EPT];
    float v[EPT];
    float lmax = -INFINITY;
    if (ok) {
        int4 a4 = *reinterpret_cast<const int4*>(src + j0);
        int4 b4 = *reinterpret_cast<const int4*>(src + j0 + 4);
        int4 c4 = *reinterpret_cast<const int4*>(dst + j0);
        int4 e4 = *reinterpret_cast<const int4*>(dst + j0 + 4);
        s_[0] = a4.x; s_[1] = a4.y; s_[2] = a4.z; s_[3] = a4.w;
        s_[4] = b4.x; s_[5] = b4.y; s_[6] = b4.z; s_[7] = b4.w;
        d_[0] = c4.x; d_[1] = c4.y; d_[2] = c4.z; d_[3] = c4.w;
        d_[4] = e4.x; d_[5] = e4.y; d_[6] = e4.z; d_[7] = e4.w;
        float svv[EPT], tvv[EPT];
#pragma unroll
        for (int k = 0; k < EPT; k++) svv[k] = sv[s_[k]];
#pragma unroll
        for (int k = 0; k < EPT; k++) tvv[k] = tv[d_[k]];
#pragma unroll
        for (int k = 0; k < EPT; k++) {
            float vv = svv[k] + tvv[k];
            vv = vv > 0.0f ? vv : LRELU_ALPHA * vv;
            v[k] = vv;
            lmax = fmaxf(lmax, vv);
        }
#pragma unroll
        for (int k = 0; k < EPT; k++) rk[k] = atomicAdd(&lcnt[s_[k] >> 7], 1);
    }
    __syncthreads();

    for (int i = tid; i < NBUCK; i += 256) {
        int c = lcnt[i];
        lbase[i] = c ? atomicAdd(&cursor[i], c) : 0;
    }
    __syncthreads();

    if (ok) {
#pragma unroll
        for (int k = 0; k < EPT; k++) {
            int b = s_[k] >> 7;
            rec[lbase[b] + rk[k]] =
                make_int2(d_[k] | ((s_[k] & (NPB - 1)) << 16), __float_as_int(v[k]));
        }
    }

    // online-softmax block stats
    float wm = wred_max(lmax);
    wm = __shfl(wm, 0, 64);
    float ev = 0.0f;
    if (ok) {
#pragma unroll
        for (int k = 0; k < EPT; k++) ev += expf(v[k] - wm);
    }
    float wsum = wred_sum(ev);

    __shared__ float rmx[4], rsm[4];
    if ((tid & 63) == 0) {
        rmx[tid >> 6] = wm;
        rsm[tid >> 6] = wsum;
    }
    __syncthreads();
    if (tid == 0) {
        float bm = fmaxf(fmaxf(rmx[0], rmx[1]), fmaxf(rmx[2], rmx[3]));
        float bs = 0.0f;
#pragma unroll
        for (int i = 0; i < 4; i++)
            bs += (rmx[i] == -INFINITY) ? 0.0f : rsm[i] * expf(rmx[i] - bm);
        pmax[blockIdx.x] = bm;
        psum[blockIdx.x] = bs;
    }
}

// combine block stats: g[0]=gmax, g[1]=1/sum
__global__ __launch_bounds__(1024) void k_rcombine(const float* __restrict__ pmax,
                                                   const float* __restrict__ psum,
                                                   int n, float* __restrict__ g) {
    __shared__ float red[16];
    __shared__ float gm_s;
    int t = threadIdx.x;
    float lmax = -INFINITY;
    for (int i = t; i < n; i += 1024) lmax = fmaxf(lmax, pmax[i]);
    float wm = wred_max(lmax);
    if ((t & 63) == 0) red[t >> 6] = wm;
    __syncthreads();
    if (t == 0) {
        float m = red[0];
        for (int i = 1; i < 16; i++) m = fmaxf(m, red[i]);
        gm_s = m;
    }
    __syncthreads();
    float gm = gm_s;
    float lsum = 0.0f;
    for (int i = t; i < n; i += 1024)
        lsum += (pmax[i] == -INFINITY) ? 0.0f : psum[i] * expf(pmax[i] - gm);
    float ws = wred_sum(lsum);
    __syncthreads();
    if ((t & 63) == 0) red[t >> 6] = ws;
    __syncthreads();
    if (t == 0) {
        float s = 0.0f;
        for (int i = 0; i < 16; i++) s += red[i];
        g[0] = gm;
        g[1] = 1.0f / s;
    }
}

// bucket gather, no atomics: 16 waves per bucket; wave w owns local nodes
// [w*8, w*8+8). Edges staged in LDS; each wave ballot-compacts its matches
// and processes 4 at a time (4 Wh-row loads in flight); 8 register slots
// selected by wave-uniform scalar cselect. Out rows written coalesced + ELU.
__global__ __launch_bounds__(1024) void k_bgather(const int* __restrict__ bbase,
                                                  const int2* __restrict__ rec,
                                                  const float* __restrict__ g,
                                                  const float* __restrict__ Wh,
                                                  float* __restrict__ out) {
    __shared__ int2 stage[512];

    const int tid = threadIdx.x;
    const int lane = tid & 63, w = tid >> 6;  // wave 0..15
    const int b = blockIdx.x;
    const float gm = g[0], ginv = g[1];
    const int e0 = bbase[b], e1 = bbase[b + 1];

    float acc[8];
#pragma unroll
    for (int k = 0; k < 8; k++) acc[k] = 0.0f;

    for (int base = e0; base < e1; base += 512) {
        int m = e1 - base;
        if (m > 512) m = 512;
        if (tid < m) stage[tid] = rec[base + tid];
        __syncthreads();

        for (int b2 = 0; b2 < m; b2 += 64) {
            int idx = b2 + lane;
            int rx = 0, ry = 0;
            bool match = false;
            if (idx < m) {
                int2 r = stage[idx];
                rx = r.x;
                ry = r.y;
                match = (((rx >> 19) & 15) == w);
            }
            unsigned long long mb = __ballot(match);
            while (mb) {
                int i0 = __ffsll(mb) - 1; mb &= mb - 1;
                int i1 = -1, i2 = -1, i3 = -1;
                if (mb) { i1 = __ffsll(mb) - 1; mb &= mb - 1; }
                if (mb) { i2 = __ffsll(mb) - 1; mb &= mb - 1; }
                if (mb) { i3 = __ffsll(mb) - 1; mb &= mb - 1; }
                bool v1 = (i1 >= 0), v2 = (i2 >= 0), v3 = (i3 >= 0);
                int j1 = v1 ? i1 : i0, j2 = v2 ? i2 : i0, j3 = v3 ? i3 : i0;

                int rx0 = __shfl(rx, i0, 64), ry0 = __shfl(ry, i0, 64);
                int rx1 = __shfl(rx, j1, 64), ry1 = __shfl(ry, j1, 64);
                int rx2 = __shfl(rx, j2, 64), ry2 = __shfl(ry, j2, 64);
                int rx3 = __shfl(rx, j3, 64), ry3 = __shfl(ry, j3, 64);

                int d0 = rx0 & 0xFFFF, s0 = (rx0 >> 16) & 7;
                int d1 = rx1 & 0xFFFF, s1 = (rx1 >> 16) & 7;
                int d2 = rx2 & 0xFFFF, s2 = (rx2 >> 16) & 7;
                int d3 = rx3 & 0xFFFF, s3 = (rx3 >> 16) & 7;

                // 4 independent row loads in flight
                float wh0 = Wh[(size_t)d0 * OUT_F + lane];
                float wh1 = Wh[(size_t)d1 * OUT_F + lane];
                float wh2 = Wh[(size_t)d2 * OUT_F + lane];
                float wh3 = Wh[(size_t)d3 * OUT_F + lane];

                float att0 = expf(__int_as_float(ry0) - gm);
                float att1 = v1 ? expf(__int_as_float(ry1) - gm) : 0.0f;
                float att2 = v2 ? expf(__int_as_float(ry2) - gm) : 0.0f;
                float att3 = v3 ? expf(__int_as_float(ry3) - gm) : 0.0f;

#pragma unroll
                for (int k = 0; k < 8; k++) {
                    acc[k] = fmaf((s0 == k) ? att0 : 0.0f, wh0, acc[k]);
                    acc[k] = fmaf((s1 == k) ? att1 : 0.0f, wh1, acc[k]);
                    acc[k] = fmaf((s2 == k) ? att2 : 0.0f, wh2, acc[k]);
                    acc[k] = fmaf((s3 == k) ? att3 : 0.0f, wh3, acc[k]);
                }
            }
        }
        __syncthreads();
    }

    // epilogue: wave w writes its 8 node rows, coalesced, ELU + ginv fused
    const int n0 = b * NPB + w * 8;
#pragma unroll
    for (int k = 0; k < 8; k++) {
        int n = n0 + k;
        if (n < N_NODES) {
            float vv = acc[k] * ginv;
            out[(size_t)n * OUT_F + lane] = vv > 0.0f ? vv : expm1f(vv);
        }
    }
}

extern "C" void kernel_launch(void* const* d_in, const int* in_sizes, int n_in,
                              void* d_out, int out_size, void* d_ws, size_t ws_size,
                              hipStream_t stream) {
    const float* x  = (const float*)d_in[0];
    const int*   ei = (const int*)d_in[1];
    const float* W  = (const float*)d_in[2];
    const float* a  = (const float*)d_in[3];
    float* out = (float*)d_out;

    const int* src = ei;            // edge_index[0]
    const int* dst = ei + N_EDGES;  // edge_index[1]

    float* ws     = (float*)d_ws;
    float* Wh     = ws;                               // 3,200,000 f
    float* sv     = Wh + (size_t)N_NODES * OUT_F;     // 50,000 f
    float* tv     = sv + N_NODES;                     // 50,000 f
    float* pmax   = tv + N_NODES;                     // 512 f
    float* psum   = pmax + 512;                       // 512 f
    float* g      = psum + 512;                       // 2 f (gmax, ginv)
    int*   bcnt   = (int*)(g + 2);                    // NBUCK i
    int*   bbase  = bcnt + NBUCK;                     // NBUCK+1 i
    int*   cursor = bbase + NBUCK + 1;                // NBUCK i
    // 16B-align rec
    size_t used = (size_t)((char*)(cursor + NBUCK) - (char*)d_ws);
    used = (used + 15) & ~(size_t)15;
    int2*  rec  = (int2*)((char*)d_ws + used);        // 800,000 int2 = 6.4 MB

    k_wh<<<(N_NODES + 63) / 64, 256, 0, stream>>>(x, W, a, Wh, sv, tv, bcnt);
    k_bhist<<<NBT, 256, 0, stream>>>(src, bcnt);
    k_bscan<<<1, 512, 0, stream>>>(bcnt, bbase, cursor);
    k_binscatter<<<NBT, 256, 0, stream>>>(src, dst, sv, tv, cursor, rec, pmax, psum);
    k_rcombine<<<1, 1024, 0, stream>>>(pmax, psum, NBT, g);
    k_bgather<<<NBUCK, 1024, 0, stream>>>(bbase, rec, g, Wh, out);
}

// Round 10
// 124.233 us; speedup vs baseline: 3.4934x; 1.4595x over previous
//
#include <hip/hip_runtime.h>
#include <math.h>

#define N_NODES 50000
#define N_EDGES 800000
#define IN_F 128
#define OUT_F 64
#define LRELU_ALPHA 0.2f

#define NPB 128                              // nodes per bucket (power of 2)
#define NBUCK ((N_NODES + NPB - 1) / NPB)    // 391
#define EPT 8                                // edges per thread (hist/scatter)
#define NBT ((N_EDGES / EPT + 255) / 256)    // 391 blocks
#define CHUNK 1024                           // gather chunk (edges)

__device__ inline float wred_max(float v) {
#pragma unroll
    for (int o = 32; o > 0; o >>= 1) v = fmaxf(v, __shfl_down(v, o, 64));
    return v;
}
__device__ inline float wred_sum(float v) {
#pragma unroll
    for (int o = 32; o > 0; o >>= 1) v += __shfl_down(v, o, 64);
    return v;
}

// K1: Wh = x @ W, register-tiled: 64x64 tile per block, 4x4 per thread.
// Block 0 additionally zeroes the bucket-histogram counters.
__global__ __launch_bounds__(256, 2) void k_wh(const float* __restrict__ x,
                                               const float* __restrict__ W,
                                               const float* __restrict__ a,
                                               float* __restrict__ Wh,
                                               float* __restrict__ sv,
                                               float* __restrict__ tv,
                                               int* __restrict__ bcnt) {
    __shared__ float xs[64 * 128];  // x tile, XOR-swizzled
    __shared__ float Ws[128 * 64];  // W, natural layout

    const int tid = threadIdx.x;
    const int row0 = blockIdx.x * 64;

    if (blockIdx.x == 0)
        for (int i = tid; i < NBUCK; i += 256) bcnt[i] = 0;

    for (int i = tid; i < 64 * 32; i += 256) {
        int rl = i >> 5, c4 = (i & 31) << 2;
        int r = row0 + rl;
        float4 v = make_float4(0.f, 0.f, 0.f, 0.f);
        if (r < N_NODES) v = *reinterpret_cast<const float4*>(x + (size_t)r * IN_F + c4);
        int sw = c4 ^ ((rl & 7) << 2);
        *reinterpret_cast<float4*>(&xs[rl * 128 + sw]) = v;
    }
    for (int i = tid; i < 128 * 16; i += 256) {
        int k = i >> 4, c4 = (i & 15) << 2;
        *reinterpret_cast<float4*>(&Ws[k * 64 + c4]) =
            *reinterpret_cast<const float4*>(W + k * 64 + c4);
    }
    __syncthreads();

    const int tx = tid & 15;
    const int ty = tid >> 4;
    const int c0 = tx << 2;
    const int rl0 = ty << 2;

    float acc[4][4] = {};
#pragma unroll 4
    for (int k = 0; k < 128; ++k) {
        float4 b = *reinterpret_cast<const float4*>(&Ws[k * 64 + c0]);
        float a0 = xs[(rl0 + 0) * 128 + (k ^ (((rl0 + 0) & 7) << 2))];
        float a1 = xs[(rl0 + 1) * 128 + (k ^ (((rl0 + 1) & 7) << 2))];
        float a2 = xs[(rl0 + 2) * 128 + (k ^ (((rl0 + 2) & 7) << 2))];
        float a3 = xs[(rl0 + 3) * 128 + (k ^ (((rl0 + 3) & 7) << 2))];
        acc[0][0] = fmaf(a0, b.x, acc[0][0]);
        acc[0][1] = fmaf(a0, b.y, acc[0][1]);
        acc[0][2] = fmaf(a0, b.z, acc[0][2]);
        acc[0][3] = fmaf(a0, b.w, acc[0][3]);
        acc[1][0] = fmaf(a1, b.x, acc[1][0]);
        acc[1][1] = fmaf(a1, b.y, acc[1][1]);
        acc[1][2] = fmaf(a1, b.z, acc[1][2]);
        acc[1][3] = fmaf(a1, b.w, acc[1][3]);
        acc[2][0] = fmaf(a2, b.x, acc[2][0]);
        acc[2][1] = fmaf(a2, b.y, acc[2][1]);
        acc[2][2] = fmaf(a2, b.z, acc[2][2]);
        acc[2][3] = fmaf(a2, b.w, acc[2][3]);
        acc[3][0] = fmaf(a3, b.x, acc[3][0]);
        acc[3][1] = fmaf(a3, b.y, acc[3][1]);
        acc[3][2] = fmaf(a3, b.z, acc[3][2]);
        acc[3][3] = fmaf(a3, b.w, acc[3][3]);
    }

    float at[4], ab[4];
#pragma unroll
    for (int i = 0; i < 4; i++) {
        at[i] = a[c0 + i];
        ab[i] = a[OUT_F + c0 + i];
    }

#pragma unroll
    for (int ri = 0; ri < 4; ++ri) {
        int r = row0 + rl0 + ri;
        float ps = 0.0f, pt = 0.0f;
#pragma unroll
        for (int ci = 0; ci < 4; ++ci) {
            ps = fmaf(acc[ri][ci], at[ci], ps);
            pt = fmaf(acc[ri][ci], ab[ci], pt);
        }
#pragma unroll
        for (int o = 1; o < 16; o <<= 1) {
            ps += __shfl_xor(ps, o, 64);
            pt += __shfl_xor(pt, o, 64);
        }
        if (r < N_NODES) {
            *reinterpret_cast<float4*>(Wh + (size_t)r * OUT_F + c0) =
                make_float4(acc[ri][0], acc[ri][1], acc[ri][2], acc[ri][3]);
            if (tx == 0) { sv[r] = ps; tv[r] = pt; }
        }
    }
}

// bucket histogram: LDS pre-aggregation, then one global atomic per bucket
__global__ __launch_bounds__(256) void k_bhist(const int* __restrict__ src,
                                               int* __restrict__ bcnt) {
    __shared__ int c[NBUCK];
    for (int i = threadIdx.x; i < NBUCK; i += 256) c[i] = 0;
    __syncthreads();
    int t = blockIdx.x * 256 + threadIdx.x;
    int j0 = t * EPT;
    if (j0 < N_EDGES) {
        int4 a4 = *reinterpret_cast<const int4*>(src + j0);
        int4 b4 = *reinterpret_cast<const int4*>(src + j0 + 4);
        atomicAdd(&c[a4.x >> 7], 1);
        atomicAdd(&c[a4.y >> 7], 1);
        atomicAdd(&c[a4.z >> 7], 1);
        atomicAdd(&c[a4.w >> 7], 1);
        atomicAdd(&c[b4.x >> 7], 1);
        atomicAdd(&c[b4.y >> 7], 1);
        atomicAdd(&c[b4.z >> 7], 1);
        atomicAdd(&c[b4.w >> 7], 1);
    }
    __syncthreads();
    for (int i = threadIdx.x; i < NBUCK; i += 256) {
        int v = c[i];
        if (v) atomicAdd(&bcnt[i], v);
    }
}

// exclusive scan of 391 bucket counts (single 512-thread block)
__global__ __launch_bounds__(512) void k_bscan(const int* __restrict__ bcnt,
                                               int* __restrict__ bbase,
                                               int* __restrict__ cursor) {
    __shared__ int s[512];
    int t = threadIdx.x;
    int c = (t < NBUCK) ? bcnt[t] : 0;
    s[t] = c;
    __syncthreads();
#pragma unroll
    for (int o = 1; o < 512; o <<= 1) {
        int v = (t >= o) ? s[t - o] : 0;
        __syncthreads();
        s[t] += v;
        __syncthreads();
    }
    if (t < NBUCK) {
        int ex = s[t] - c;
        bbase[t] = ex;
        cursor[t] = ex;
    }
    if (t == 0) bbase[NBUCK] = N_EDGES;
}

// bucket scatter: LDS ranks + one global reserve atomic per (block,bucket),
// contiguous run writes; fused edge score + online-softmax block stats.
__global__ __launch_bounds__(256) void k_binscatter(const int* __restrict__ src,
                                                    const int* __restrict__ dst,
                                                    const float* __restrict__ sv,
                                                    const float* __restrict__ tv,
                                                    int* __restrict__ cursor,
                                                    int2* __restrict__ rec,
                                                    float* __restrict__ pmax,
                                                    float* __restrict__ psum) {
    __shared__ int lcnt[NBUCK];
    __shared__ int lbase[NBUCK];
    const int tid = threadIdx.x;
    for (int i = tid; i < NBUCK; i += 256) lcnt[i] = 0;
    __syncthreads();

    int t = blockIdx.x * 256 + tid;
    int j0 = t * EPT;
    bool ok = (j0 < N_EDGES);  // N_EDGES % EPT == 0 -> all-or-nothing per thread

    int s_[EPT], d_[EPT], rk[EPT];
    float v[EPT];
    float lmax = -INFINITY;
    if (ok) {
        int4 a4 = *reinterpret_cast<const int4*>(src + j0);
        int4 b4 = *reinterpret_cast<const int4*>(src + j0 + 4);
        int4 c4 = *reinterpret_cast<const int4*>(dst + j0);
        int4 e4 = *reinterpret_cast<const int4*>(dst + j0 + 4);
        s_[0] = a4.x; s_[1] = a4.y; s_[2] = a4.z; s_[3] = a4.w;
        s_[4] = b4.x; s_[5] = b4.y; s_[6] = b4.z; s_[7] = b4.w;
        d_[0] = c4.x; d_[1] = c4.y; d_[2] = c4.z; d_[3] = c4.w;
        d_[4] = e4.x; d_[5] = e4.y; d_[6] = e4.z; d_[7] = e4.w;
        float svv[EPT], tvv[EPT];
#pragma unroll
        for (int k = 0; k < EPT; k++) svv[k] = sv[s_[k]];
#pragma unroll
        for (int k = 0; k < EPT; k++) tvv[k] = tv[d_[k]];
#pragma unroll
        for (int k = 0; k < EPT; k++) {
            float vv = svv[k] + tvv[k];
            vv = vv > 0.0f ? vv : LRELU_ALPHA * vv;
            v[k] = vv;
            lmax = fmaxf(lmax, vv);
        }
#pragma unroll
        for (int k = 0; k < EPT; k++) rk[k] = atomicAdd(&lcnt[s_[k] >> 7], 1);
    }
    __syncthreads();

    for (int i = tid; i < NBUCK; i += 256) {
        int c = lcnt[i];
        lbase[i] = c ? atomicAdd(&cursor[i], c) : 0;
    }
    __syncthreads();

    if (ok) {
#pragma unroll
        for (int k = 0; k < EPT; k++) {
            int b = s_[k] >> 7;
            rec[lbase[b] + rk[k]] =
                make_int2(d_[k] | ((s_[k] & (NPB - 1)) << 16), __float_as_int(v[k]));
        }
    }

    // online-softmax block stats
    float wm = wred_max(lmax);
    wm = __shfl(wm, 0, 64);
    float ev = 0.0f;
    if (ok) {
#pragma unroll
        for (int k = 0; k < EPT; k++) ev += expf(v[k] - wm);
    }
    float wsum = wred_sum(ev);

    __shared__ float rmx[4], rsm[4];
    if ((tid & 63) == 0) {
        rmx[tid >> 6] = wm;
        rsm[tid >> 6] = wsum;
    }
    __syncthreads();
    if (tid == 0) {
        float bm = fmaxf(fmaxf(rmx[0], rmx[1]), fmaxf(rmx[2], rmx[3]));
        float bs = 0.0f;
#pragma unroll
        for (int i = 0; i < 4; i++)
            bs += (rmx[i] == -INFINITY) ? 0.0f : rsm[i] * expf(rmx[i] - bm);
        pmax[blockIdx.x] = bm;
        psum[blockIdx.x] = bs;
    }
}

// combine block stats: g[0]=gmax, g[1]=1/sum
__global__ __launch_bounds__(1024) void k_rcombine(const float* __restrict__ pmax,
                                                   const float* __restrict__ psum,
                                                   int n, float* __restrict__ g) {
    __shared__ float red[16];
    __shared__ float gm_s;
    int t = threadIdx.x;
    float lmax = -INFINITY;
    for (int i = t; i < n; i += 1024) lmax = fmaxf(lmax, pmax[i]);
    float wm = wred_max(lmax);
    if ((t & 63) == 0) red[t >> 6] = wm;
    __syncthreads();
    if (t == 0) {
        float m = red[0];
        for (int i = 1; i < 16; i++) m = fmaxf(m, red[i]);
        gm_s = m;
    }
    __syncthreads();
    float gm = gm_s;
    float lsum = 0.0f;
    for (int i = t; i < n; i += 1024)
        lsum += (pmax[i] == -INFINITY) ? 0.0f : psum[i] * expf(pmax[i] - gm);
    float ws = wred_sum(lsum);
    __syncthreads();
    if ((t & 63) == 0) red[t >> 6] = ws;
    __syncthreads();
    if (t == 0) {
        float s = 0.0f;
        for (int i = 0; i < 16; i++) s += red[i];
        g[0] = gm;
        g[1] = 1.0f / s;
    }
}

// bucket gather: fused in-LDS counting sort by local node + direct accumulate.
// 16 waves/block; chunk of 1024 edges held in REGISTERS (1/thread), LDS hist
// (128 counters) + shfl-scan + LDS re-scatter to sorted[]; then wave w walks
// nodes w*8..w*8+7: per edge 1 broadcast LDS read + 1 coalesced Wh row + 1 FMA.
__global__ __launch_bounds__(1024) void k_bgather(const int* __restrict__ bbase,
                                                  const int2* __restrict__ rec,
                                                  const float* __restrict__ g,
                                                  const float* __restrict__ Wh,
                                                  float* __restrict__ out) {
    __shared__ int2 sorted[CHUNK];               // 8 KB
    __shared__ int scnt[NPB], soff[NPB], shead[NPB];

    const int tid = threadIdx.x;
    const int lane = tid & 63, w = tid >> 6;     // wave 0..15
    const int b = blockIdx.x;
    const float gm = g[0], ginv = g[1];
    const int e0 = bbase[b], e1 = bbase[b + 1];

    float acc[8];
#pragma unroll
    for (int k = 0; k < 8; k++) acc[k] = 0.0f;

    for (int base = e0; base < e1; base += CHUNK) {
        int m = e1 - base;
        if (m > CHUNK) m = CHUNK;

        // edge record in register; LDS histogram by local node id
        int2 r = make_int2(0, 0);
        int ln = 0;
        if (tid < NPB) scnt[tid] = 0;
        __syncthreads();
        if (tid < m) {
            r = rec[base + tid];
            ln = (r.x >> 16) & (NPB - 1);
            atomicAdd(&scnt[ln], 1);
        }
        __syncthreads();

        // exclusive scan of 128 counters: wave 0, lane t owns nodes 2t,2t+1
        if (tid < 64) {
            int c0 = scnt[2 * tid], c1 = scnt[2 * tid + 1];
            int s = c0 + c1;
            int run = s;
#pragma unroll
            for (int o = 1; o < 64; o <<= 1) {
                int src_ln = (tid >= o) ? (tid - o) : tid;
                int t2 = __shfl(run, src_ln, 64);
                if (tid >= o) run += t2;
            }
            int excl = run - s;
            soff[2 * tid] = excl;
            soff[2 * tid + 1] = excl + c0;
            shead[2 * tid] = excl;
            shead[2 * tid + 1] = excl + c0;
        }
        __syncthreads();

        // re-scatter from register into sorted[] (node-grouped)
        if (tid < m) {
            int pos = atomicAdd(&shead[ln], 1);
            sorted[pos] = make_int2(r.x & 0xFFFF, r.y);
        }
        __syncthreads();

        // wave w accumulates its 8 nodes; 4-unrolled, 2 partial sums
#pragma unroll
        for (int k = 0; k < 8; k++) {
            int node = w * 8 + k;
            int lo = soff[node], c = scnt[node];
            float p0 = 0.0f, p1 = 0.0f;
            int i = 0;
            for (; i + 3 < c; i += 4) {
                int2 q0 = sorted[lo + i];
                int2 q1 = sorted[lo + i + 1];
                int2 q2 = sorted[lo + i + 2];
                int2 q3 = sorted[lo + i + 3];
                float w0 = Wh[(size_t)q0.x * OUT_F + lane];
                float w1 = Wh[(size_t)q1.x * OUT_F + lane];
                float w2 = Wh[(size_t)q2.x * OUT_F + lane];
                float w3 = Wh[(size_t)q3.x * OUT_F + lane];
                p0 = fmaf(expf(__int_as_float(q0.y) - gm), w0, p0);
                p1 = fmaf(expf(__int_as_float(q1.y) - gm), w1, p1);
                p0 = fmaf(expf(__int_as_float(q2.y) - gm), w2, p0);
                p1 = fmaf(expf(__int_as_float(q3.y) - gm), w3, p1);
            }
            for (; i < c; i++) {
                int2 q0 = sorted[lo + i];
                p0 = fmaf(expf(__int_as_float(q0.y) - gm),
                          Wh[(size_t)q0.x * OUT_F + lane], p0);
            }
            acc[k] += p0 + p1;
        }
        __syncthreads();
    }

    // epilogue: wave w writes its 8 node rows, coalesced, ELU + ginv fused
    const int n0 = b * NPB + w * 8;
#pragma unroll
    for (int k = 0; k < 8; k++) {
        int n = n0 + k;
        if (n < N_NODES) {
            float vv = acc[k] * ginv;
            out[(size_t)n * OUT_F + lane] = vv > 0.0f ? vv : expm1f(vv);
        }
    }
}

extern "C" void kernel_launch(void* const* d_in, const int* in_sizes, int n_in,
                              void* d_out, int out_size, void* d_ws, size_t ws_size,
                              hipStream_t stream) {
    const float* x  = (const float*)d_in[0];
    const int*   ei = (const int*)d_in[1];
    const float* W  = (const float*)d_in[2];
    const float* a  = (const float*)d_in[3];
    float* out = (float*)d_out;

    const int* src = ei;            // edge_index[0]
    const int* dst = ei + N_EDGES;  // edge_index[1]

    float* ws     = (float*)d_ws;
    float* Wh     = ws;                               // 3,200,000 f
    float* sv     = Wh + (size_t)N_NODES * OUT_F;     // 50,000 f
    float* tv     = sv + N_NODES;                     // 50,000 f
    float* pmax   = tv + N_NODES;                     // 512 f
    float* psum   = pmax + 512;                       // 512 f
    float* g      = psum + 512;                       // 2 f (gmax, ginv)
    int*   bcnt   = (int*)(g + 2);                    // NBUCK i
    int*   bbase  = bcnt + NBUCK;                     // NBUCK+1 i
    int*   cursor = bbase + NBUCK + 1;                // NBUCK i
    // 16B-align rec
    size_t used = (size_t)((char*)(cursor + NBUCK) - (char*)d_ws);
    used = (used + 15) & ~(size_t)15;
    int2*  rec  = (int2*)((char*)d_ws + used);        // 800,000 int2 = 6.4 MB

    k_wh<<<(N_NODES + 63) / 64, 256, 0, stream>>>(x, W, a, Wh, sv, tv, bcnt);
    k_bhist<<<NBT, 256, 0, stream>>>(src, bcnt);
    k_bscan<<<1, 512, 0, stream>>>(bcnt, bbase, cursor);
    k_binscatter<<<NBT, 256, 0, stream>>>(src, dst, sv, tv, cursor, rec, pmax, psum);
    k_rcombine<<<1, 1024, 0, stream>>>(pmax, psum, NBT, g);
    k_bgather<<<NBUCK, 1024, 0, stream>>>(bbase, rec, g, Wh, out);
}